// Round 8
// baseline (979.561 us; speedup 1.0000x reference)
//
#include <hip/hip_runtime.h>

namespace {

constexpr int kB = 64;
constexpr int kL = 4096;
constexpr float kLrW = 1.0f / 64.0f;
constexpr float kLrF = 1.0f / 128.0f;
constexpr float kGradMax = 30.0f;
constexpr float kEps = 1e-9f;
constexpr int kPF = 8;
constexpr int kNC = kL / kPF;

#define DPP_ADD_F32(v, ctrl)                                                   \
    v += __int_as_float(__builtin_amdgcn_update_dpp(                           \
        0, __float_as_int(v), (ctrl), 0xF, 0xF, true))

__device__ __forceinline__ float rl(float v, int l) {
    return __int_as_float(__builtin_amdgcn_readlane(__float_as_int(v), l));
}
__device__ __forceinline__ float frcp(float x) { return __builtin_amdgcn_rcpf(x); }
__device__ __forceinline__ float frsq(float x) { return __builtin_amdgcn_rsqf(x); }

typedef const __attribute__((address_space(1))) float gfloat;
typedef __attribute__((address_space(3))) float lfloat;

__global__ __launch_bounds__(64, 1) void adf_kernel(
    const float* __restrict__ u_r, const float* __restrict__ u_i,
    const float* __restrict__ x_r, const float* __restrict__ x_i,
    const float* __restrict__ w0r_g, const float* __restrict__ w0i_g,
    const float* __restrict__ f0r_g, const float* __restrict__ f0i_g,
    float* __restrict__ out)
{
    // LDS staging: async global_load_lds holds no VGPRs in flight -> real
    // 2-chunk prefetch depth (the reg-buffer version never materialized:
    // VGPR_Count 52 in r1-r7 proved loads were sunk to consumption).
    __shared__ float lu[2][kPF][64];
    __shared__ float lq[2][kPF][64];
    __shared__ float lx[2][64];

    const int b = blockIdx.x;
    const int lane = threadIdx.x;
    const int half = lane >> 5;
    const int tap  = lane & 31;
    const bool lo  = (half == 0);

    const int wbase = b * 128 + half * 64 + tap;
    float wAr = w0r_g[wbase],      wAi = w0i_g[wbase];
    float wBr = w0r_g[wbase + 32], wBi = w0i_g[wbase + 32];

    float fr = f0r_g[b * 2 + half];
    float fi = f0i_g[b * 2 + half];
    const float invf0 = frsq(fmaf(fr, fr, fi * fi));
    float psr = fr * invf0, psm = -fi * invf0;   // psi = conj(f)/|f|

    // u element for (t, tap, j) at flat b*L*64 + t*64 + (tap*2+j); lane l
    // stages element l -> lds slot l (linear, matches global_load_lds).
    gfloat* gu = (gfloat*)u_r + (size_t)b * kL * 64 + lane;
    gfloat* gq = (gfloat*)u_i + (size_t)b * kL * 64 + lane;
    // x gather: lanes 0..15 -> x_r floats, 16..31 -> x_i floats; upper half dups.
    const int xl = lane & 31;
    gfloat* gx = (xl < 16)
        ? ((gfloat*)x_r + (size_t)b * kL * 2 + xl)
        : ((gfloat*)x_i + (size_t)b * kL * 2 + (xl - 16));
    float2* __restrict__ ob2 = (float2*)out + (size_t)b * kL * 2;

    auto stage = [&](int chunk) {   // exactly 17 vmem ops, always
        const int par = chunk & 1;
#pragma unroll
        for (int s = 0; s < kPF; ++s) {
            __builtin_amdgcn_global_load_lds(gu + (size_t)(chunk * kPF + s) * 64,
                                             (lfloat*)&lu[par][s][0], 4, 0, 0);
            __builtin_amdgcn_global_load_lds(gq + (size_t)(chunk * kPF + s) * 64,
                                             (lfloat*)&lq[par][s][0], 4, 0, 0);
        }
        __builtin_amdgcn_global_load_lds(gx + chunk * 16,
                                         (lfloat*)&lx[par][0], 4, 0, 0);
    };

    auto ldu = [&](int par, int s) { return *(const float2*)&lu[par][s][tap * 2]; };
    auto ldq = [&](int par, int s) { return *(const float2*)&lq[par][s][tap * 2]; };

    stage(0);
    stage(1);
    asm volatile("s_waitcnt vmcnt(17)" ::: "memory");   // chunk 0 resident

    float2 cu = ldu(0, 0), cq = ldq(0, 0);   // u(t)
    float2 nu = ldu(0, 1), nq = ldq(0, 1);   // u(t+1)

    float prC, piC;   // reduced partial chains for v(t)
    {
        float pr = wAr * cu.x;
        pr = fmaf(-wAi, cq.x, pr); pr = fmaf(wBr, cu.y, pr); pr = fmaf(-wBi, cq.y, pr);
        float pi = wAr * cq.x;
        pi = fmaf(wAi, cu.x, pi); pi = fmaf(wBr, cq.y, pi); pi = fmaf(wBi, cu.y, pi);
        DPP_ADD_F32(pr, 0x111); DPP_ADD_F32(pi, 0x111);
        DPP_ADD_F32(pr, 0x112); DPP_ADD_F32(pi, 0x112);
        DPP_ADD_F32(pr, 0x114); DPP_ADD_F32(pi, 0x114);
        DPP_ADD_F32(pr, 0x118); DPP_ADD_F32(pi, 0x118);
        DPP_ADD_F32(pr, 0x142); DPP_ADD_F32(pi, 0x142);
        prC = pr; piC = pi;
    }

    float sdpr = 0.f, sdpi = 0.f;   // su(t)*d(t)*psi(t)
    float kR[kPF], kI[kPF];

    for (int c = 0; c < kNC; ++c) {
        const int par = c & 1;
        // drain stage(c); stores(c-1)=8 + stage(c+1)=17 may remain in flight
        asm volatile("s_waitcnt vmcnt(25)" ::: "memory");

        // ---- preamble: su + d for this chunk (state-independent, ILP-rich) ----
        float su[kPF], dr[kPF], di[kPF];
        {
            float e[kPF];
#pragma unroll
            for (int s = 0; s < kPF; ++s) {
                const float2 uu = ldu(par, s), qq = ldq(par, s);
                float t0 = uu.x * uu.x;
                t0 = fmaf(uu.y, uu.y, t0);
                t0 = fmaf(qq.x, qq.x, t0);
                t0 = fmaf(qq.y, qq.y, t0);
                e[s] = t0;
            }
#pragma unroll
            for (int s = 0; s < kPF; ++s) { DPP_ADD_F32(e[s], 0x111); }
#pragma unroll
            for (int s = 0; s < kPF; ++s) { DPP_ADD_F32(e[s], 0x112); }
#pragma unroll
            for (int s = 0; s < kPF; ++s) { DPP_ADD_F32(e[s], 0x114); }
#pragma unroll
            for (int s = 0; s < kPF; ++s) { DPP_ADD_F32(e[s], 0x118); }
#pragma unroll
            for (int s = 0; s < kPF; ++s) { DPP_ADD_F32(e[s], 0x142); }
#pragma unroll
            for (int s = 0; s < kPF; ++s)
                su[s] = kLrW * frcp(rl(e[s], 31) + kEps);
#pragma unroll
            for (int s = 0; s < kPF; ++s) {
                const float2 xr_ = *(const float2*)&lx[par][2 * s];
                const float2 xi_ = *(const float2*)&lx[par][16 + 2 * s];
                dr[s] = lo ? xr_.x : xr_.y;
                di[s] = lo ? xi_.x : xi_.y;
            }
        }

        // chunk-entry sdp from carried psi
        {
            const float dpr = fmaf(dr[0], psr, -di[0] * psm);
            const float dpi = fmaf(dr[0], psm,  di[0] * psr);
            sdpr = su[0] * dpr;
            sdpi = su[0] * dpi;
        }

#pragma unroll
        for (int s = 0; s < kPF; ++s) {
            // bodies 6,7 prefetch next chunk's slices 0,1: stage(c+1) must have
            // landed (issued ~1 chunk ago -> this wait is near-free)
            if (s == 6) asm volatile("s_waitcnt vmcnt(0)" ::: "memory");
            const int s2 = (s + 2) & 7;
            const int pb = (s + 2 >= kPF) ? (par ^ 1) : par;
            const float2 fu = ldu(pb, s2), fq = ldq(pb, s2);   // u(t+2)

            // v(t) broadcast
            const float v0r = rl(prC, 31), v1r = rl(prC, 63);
            const float v0i = rl(piC, 31), v1i = rl(piC, 63);
            const float vr = lo ? v0r : v1r;
            const float vi = lo ? v0i : v1i;

            // critical: tau -> w-update -> partials(t+1) -> DPP chain
            const float tr = fmaf(-su[s], vr, sdpr);
            const float ti = fmaf(-su[s], vi, sdpi);
            wAr = fmaf(tr, cu.x, fmaf(ti, cq.x, wAr));
            wAi = fmaf(ti, cu.x, fmaf(-tr, cq.x, wAi));
            wBr = fmaf(tr, cu.y, fmaf(ti, cq.y, wBr));
            wBi = fmaf(ti, cu.y, fmaf(-tr, cq.y, wBi));

            float pr = wAr * nu.x;
            pr = fmaf(-wAi, nq.x, pr); pr = fmaf(wBr, nu.y, pr); pr = fmaf(-wBi, nq.y, pr);
            float pi = wAr * nq.x;
            pi = fmaf(wAi, nu.x, pi); pi = fmaf(wBr, nq.y, pi); pi = fmaf(wBi, nu.y, pi);
            DPP_ADD_F32(pr, 0x111); DPP_ADD_F32(pi, 0x111);
            DPP_ADD_F32(pr, 0x112); DPP_ADD_F32(pi, 0x112);
            DPP_ADD_F32(pr, 0x114); DPP_ADD_F32(pi, 0x114);
            DPP_ADD_F32(pr, 0x118); DPP_ADD_F32(pi, 0x118);
            DPP_ADD_F32(pr, 0x142); DPP_ADD_F32(pi, 0x142);

            // f-path(t): independent of the DPP chain above -> fills its shadow
            const float kr = fmaf(vr, fr, -vi * fi);
            const float ki = fmaf(vr, fi,  vi * fr);
            kR[s] = kr; kI[s] = ki;
            const float efr = dr[s] - kr, efi = di[s] - ki;
            float ven = v0r * v0r;
            ven = fmaf(v0i, v0i, ven);
            ven = fmaf(v1r, v1r, ven);
            ven = fmaf(v1i, v1i, ven);
            const float nv = frcp(ven + kEps);
            float hr = efr * vr; hr = fmaf(efi, vi, hr);   // h = ef*conj(v)/ven
            float hi = efi * vr; hi = fmaf(-efr, vi, hi);
            hr *= nv; hi *= nv;
            float mg = hr * hr; mg = fmaf(hi, hi, mg);
            const float sc = fminf(1.0f, kGradMax * frsq(mg));
            const float scl = kLrF * sc;
            fr = fmaf(scl, hr, fr);
            fi = fmaf(scl, hi, fi);
            const float invf = frsq(fmaf(fr, fr, fi * fi));
            psr = fr * invf; psm = -fi * invf;
            if (s + 1 < kPF) {
                const float dpr = fmaf(dr[s + 1], psr, -di[s + 1] * psm);
                const float dpi = fmaf(dr[s + 1], psm,  di[s + 1] * psr);
                sdpr = su[s + 1] * dpr;
                sdpi = su[s + 1] * dpi;
            }

            prC = pr; piC = pi;
            cu = nu; cq = nq; nu = fu; nq = fq;
        }

        // batched output stores (8 vmem ops)
        if (tap == 0) {
#pragma unroll
            for (int s = 0; s < kPF; ++s)
                ob2[(size_t)(c * kPF + s) * 2 + half] = make_float2(kR[s], kI[s]);
        }
        // stage chunk c+2 into the buffer this chunk just finished reading
        stage((c + 2 < kNC) ? c + 2 : kNC - 1);
    }
}

} // namespace

extern "C" void kernel_launch(void* const* d_in, const int* in_sizes, int n_in,
                              void* d_out, int out_size, void* d_ws, size_t ws_size,
                              hipStream_t stream) {
    const float* u_r  = (const float*)d_in[0];
    const float* u_i  = (const float*)d_in[1];
    const float* x_r  = (const float*)d_in[2];
    const float* x_i  = (const float*)d_in[3];
    const float* w0_r = (const float*)d_in[4];
    const float* w0_i = (const float*)d_in[5];
    const float* f0_r = (const float*)d_in[6];
    const float* f0_i = (const float*)d_in[7];
    float* out = (float*)d_out;

    dim3 grid(kB);
    dim3 block(64);
    adf_kernel<<<grid, block, 0, stream>>>(u_r, u_i, x_r, x_i,
                                           w0_r, w0_i, f0_r, f0_i, out);
}

// Round 10
// 929.403 us; speedup vs baseline: 1.0540x; 1.0540x over previous
//
#include <hip/hip_runtime.h>

namespace {

constexpr int kB = 64;
constexpr int kL = 4096;
constexpr float kLrW = 1.0f / 64.0f;
constexpr float kLrF = 1.0f / 128.0f;
constexpr float kGradMax = 30.0f;
constexpr float kEps = 1e-9f;
constexpr int kPF = 8;
constexpr int kNC = kL / kPF;

#define DPP_ADD_F32(v, ctrl)                                                   \
    v += __int_as_float(__builtin_amdgcn_update_dpp(                           \
        0, __float_as_int(v), (ctrl), 0xF, 0xF, true))

__device__ __forceinline__ float rl(float v, int l) {
    return __int_as_float(__builtin_amdgcn_readlane(__float_as_int(v), l));
}
__device__ __forceinline__ float frcp(float x) { return __builtin_amdgcn_rcpf(x); }
__device__ __forceinline__ float frsq(float x) { return __builtin_amdgcn_rsqf(x); }

// Circular all-reduce within each row of 16: every lane ends with its row sum.
__device__ __forceinline__ float rowsum16(float v) {
    DPP_ADD_F32(v, 0x121);  // row_ror:1
    DPP_ADD_F32(v, 0x122);  // row_ror:2
    DPP_ADD_F32(v, 0x124);  // row_ror:4
    DPP_ADD_F32(v, 0x128);  // row_ror:8
    return v;
}

typedef unsigned u32x2v __attribute__((ext_vector_type(2)));

// Row-pair sum: in = per-lane row-16 sums, out = sum of the two rows of each
// 32-half, uniform in that half. Builtin handles the permlane read-after-VALU
// hazard nops (the r9 inline asm missed them -> stale operand -> corruption).
__device__ __forceinline__ float pairsum16(float v) {
#if __has_builtin(__builtin_amdgcn_permlane16_swap)
    u32x2v r = __builtin_amdgcn_permlane16_swap(__float_as_uint(v),
                                                __float_as_uint(v),
                                                false, false);
    return __uint_as_float(r[0]) + __uint_as_float(r[1]);
#else
    float a = v, b2;
    asm("v_mov_b32 %1, %0\n\t"
        "s_nop 1\n\t"
        "v_permlane16_swap_b32 %0, %1"
        : "+v"(a), "=&v"(b2));
    return a + b2;
#endif
}

// Half-pair sum: out = v(lane) + v(lane^32), uniform across the wave.
__device__ __forceinline__ float pairsum32(float v) {
#if __has_builtin(__builtin_amdgcn_permlane32_swap)
    u32x2v r = __builtin_amdgcn_permlane32_swap(__float_as_uint(v),
                                                __float_as_uint(v),
                                                false, false);
    return __uint_as_float(r[0]) + __uint_as_float(r[1]);
#else
    float a = v, b2;
    asm("v_mov_b32 %1, %0\n\t"
        "s_nop 1\n\t"
        "v_permlane32_swap_b32 %0, %1"
        : "+v"(a), "=&v"(b2));
    return a + b2;
#endif
}

typedef const __attribute__((address_space(1))) float gfloat;
typedef __attribute__((address_space(3))) float lfloat;

// ---------- precompute: su[b,t] = lrW/(sum|u|^2+eps), xd[b,t] = packed d ----
__global__ __launch_bounds__(256, 1) void pre_kernel(
    const float* __restrict__ u_r, const float* __restrict__ u_i,
    const float* __restrict__ x_r, const float* __restrict__ x_i,
    float* __restrict__ su_ws, float4* __restrict__ xd_ws)
{
    const int lane = threadIdx.x & 63;
    const int idx = blockIdx.x * 4 + (threadIdx.x >> 6);   // flat b*L + t
    const float a = u_r[(size_t)idx * 64 + lane];
    const float c = u_i[(size_t)idx * 64 + lane];
    float e = fmaf(a, a, c * c);
    e = rowsum16(e);
    e = pairsum16(e);
    e = pairsum32(e);
    if (lane == 0) {
        su_ws[idx] = kLrW * frcp(e + kEps);
        const float2 xr = *(const float2*)(x_r + (size_t)idx * 2);
        const float2 xi = *(const float2*)(x_i + (size_t)idx * 2);
        xd_ws[idx] = make_float4(xr.x, xr.y, xi.x, xi.y);
    }
}

// ---------- main scan kernel (fast path) -----------------------------------
__global__ __launch_bounds__(64, 1) void adf_kernel(
    const float* __restrict__ u_r, const float* __restrict__ u_i,
    const float* __restrict__ w0r_g, const float* __restrict__ w0i_g,
    const float* __restrict__ f0r_g, const float* __restrict__ f0i_g,
    const float* __restrict__ su_p, const float4* __restrict__ xd_p,
    float* __restrict__ out)
{
    __shared__ float lu[2][kPF][64];
    __shared__ float lq[2][kPF][64];

    const int b = blockIdx.x;
    const int lane = threadIdx.x;
    const int half = lane >> 5;
    const int tap  = lane & 31;
    const bool lo  = (half == 0);

    const int wbase = b * 128 + half * 64 + tap;
    float wAr = w0r_g[wbase],      wAi = w0i_g[wbase];
    float wBr = w0r_g[wbase + 32], wBi = w0i_g[wbase + 32];

    float fr = f0r_g[b * 2 + half];
    float fi = f0i_g[b * 2 + half];
    const float invf0 = frsq(fmaf(fr, fr, fi * fi));
    float psr = fr * invf0, psm = -fi * invf0;   // psi = conj(f)/|f|

    gfloat* gu = (gfloat*)u_r + (size_t)b * kL * 64 + lane;
    gfloat* gq = (gfloat*)u_i + (size_t)b * kL * 64 + lane;
    float2* __restrict__ ob2 = (float2*)out + (size_t)b * kL * 2;

    auto stage = [&](int chunk) {   // exactly 16 vmem ops
        const int par = chunk & 1;
#pragma unroll
        for (int s = 0; s < kPF; ++s) {
            __builtin_amdgcn_global_load_lds(gu + (size_t)(chunk * kPF + s) * 64,
                                             (lfloat*)&lu[par][s][0], 4, 0, 0);
            __builtin_amdgcn_global_load_lds(gq + (size_t)(chunk * kPF + s) * 64,
                                             (lfloat*)&lq[par][s][0], 4, 0, 0);
        }
    };
    auto ldu = [&](int par, int s) { return *(const float2*)&lu[par][s][tap * 2]; };
    auto ldq = [&](int par, int s) { return *(const float2*)&lq[par][s][tap * 2]; };

    stage(0);
    stage(1);
    asm volatile("s_waitcnt vmcnt(16)" ::: "memory");   // chunk 0 resident

    float2 cu = ldu(0, 0), cq = ldq(0, 0);   // u(t)
    float2 nu = ldu(0, 1), nq = ldq(0, 1);   // u(t+1)

    // prologue: v(0) reduced, uniform per half
    float prC, piC;
    {
        float pr = wAr * cu.x;
        pr = fmaf(-wAi, cq.x, pr); pr = fmaf(wBr, cu.y, pr); pr = fmaf(-wBi, cq.y, pr);
        float pi = wAr * cq.x;
        pi = fmaf(wAi, cu.x, pi); pi = fmaf(wBr, cq.y, pi); pi = fmaf(wBi, cu.y, pi);
        pr = rowsum16(pr); pi = rowsum16(pi);
        prC = pairsum16(pr); piC = pairsum16(pi);
    }

    float sdpr = 0.f, sdpi = 0.f;
    float kR[kPF], kI[kPF];

    for (int c = 0; c < kNC; ++c) {
        const int par = c & 1;
        const int base = b * kL + c * kPF;

        float4 xq[kPF];
        float suv[kPF];
#pragma unroll
        for (int s = 0; s < kPF; ++s) xq[s] = xd_p[base + s];
#pragma unroll
        for (int s = 0; s < kPF; ++s) suv[s] = su_p[base + s];

        {   // chunk-entry sdp = su*d*psi from carried psi
            const float dr0 = lo ? xq[0].x : xq[0].y;
            const float di0 = lo ? xq[0].z : xq[0].w;
            sdpr = suv[0] * fmaf(dr0, psr, -di0 * psm);
            sdpi = suv[0] * fmaf(dr0, psm,  di0 * psr);
        }

#pragma unroll
        for (int s = 0; s < kPF; ++s) {
            if (s == 6) asm volatile("s_waitcnt vmcnt(0)" ::: "memory");
            const float2 fu = (s < 6) ? ldu(par, s + 2) : ldu(par ^ 1, s - 6);
            const float2 fq = (s < 6) ? ldq(par, s + 2) : ldq(par ^ 1, s - 6);

            const float vr = prC, vi = piC;   // v(t), uniform per half

            // critical: tau -> w-update -> partials(t+1) -> reduce
            const float tr = fmaf(-suv[s], vr, sdpr);
            const float ti = fmaf(-suv[s], vi, sdpi);
            wAr = fmaf(tr, cu.x, fmaf(ti, cq.x, wAr));
            wAi = fmaf(ti, cu.x, fmaf(-tr, cq.x, wAi));
            wBr = fmaf(tr, cu.y, fmaf(ti, cq.y, wBr));
            wBi = fmaf(ti, cu.y, fmaf(-tr, cq.y, wBi));

            float pr = wAr * nu.x;
            pr = fmaf(-wAi, nq.x, pr); pr = fmaf(wBr, nu.y, pr); pr = fmaf(-wBi, nq.y, pr);
            float pi = wAr * nq.x;
            pi = fmaf(wAi, nu.x, pi); pi = fmaf(wBr, nq.y, pi); pi = fmaf(wBi, nu.y, pi);
            DPP_ADD_F32(pr, 0x121); DPP_ADD_F32(pi, 0x121);
            DPP_ADD_F32(pr, 0x122); DPP_ADD_F32(pi, 0x122);
            DPP_ADD_F32(pr, 0x124); DPP_ADD_F32(pi, 0x124);
            DPP_ADD_F32(pr, 0x128); DPP_ADD_F32(pi, 0x128);
            pr = pairsum16(pr);
            pi = pairsum16(pi);

            // f-path for step t (independent of the reduce above)
            const float dr = lo ? xq[s].x : xq[s].y;
            const float di = lo ? xq[s].z : xq[s].w;
            const float kr = fmaf(vr, fr, -vi * fi);
            const float ki = fmaf(vr, fi,  vi * fr);
            kR[s] = kr; kI[s] = ki;
            const float efr = dr - kr, efi = di - ki;
            float mv2 = fmaf(vr, vr, vi * vi);
            const float ven = pairsum32(mv2) + kEps;
            const float nv = frcp(ven);
            const float hr = fmaf(efi, vi, efr * vr) * nv;   // -gf
            const float hi = fmaf(-efr, vi, efi * vr) * nv;
            const float mg = fmaf(hi, hi, hr * hr);
            const float sc = fminf(1.0f, kGradMax * frsq(mg));
            const float scl = kLrF * sc;
            fr = fmaf(scl, hr, fr);
            fi = fmaf(scl, hi, fi);
            const float invf = frsq(fmaf(fr, fr, fi * fi));
            psr = fr * invf; psm = -fi * invf;
            if (s + 1 < kPF) {
                const float dnr = lo ? xq[s + 1].x : xq[s + 1].y;
                const float dni = lo ? xq[s + 1].z : xq[s + 1].w;
                sdpr = suv[s + 1] * fmaf(dnr, psr, -dni * psm);
                sdpi = suv[s + 1] * fmaf(dnr, psm,  dni * psr);
            }

            prC = pr; piC = pi;
            cu = nu; cq = nq; nu = fu; nq = fq;
        }

        if (tap == 0) {
#pragma unroll
            for (int s = 0; s < kPF; ++s)
                ob2[(size_t)(c * kPF + s) * 2 + half] = make_float2(kR[s], kI[s]);
        }
        // all chunk-c ds_reads executed before restaging this parity
        asm volatile("s_waitcnt lgkmcnt(0)" ::: "memory");
        stage((c + 2 < kNC) ? c + 2 : kNC - 1);
    }
}

// ---------- fallback (r7, 838 us) if ws too small --------------------------
__global__ __launch_bounds__(64, 1) void adf_fb(
    const float* __restrict__ u_r, const float* __restrict__ u_i,
    const float* __restrict__ x_r, const float* __restrict__ x_i,
    const float* __restrict__ w0r_g, const float* __restrict__ w0i_g,
    const float* __restrict__ f0r_g, const float* __restrict__ f0i_g,
    float* __restrict__ out)
{
    const int b = blockIdx.x;
    const int lane = threadIdx.x;
    const int half = lane >> 5;
    const int tap  = lane & 31;
    const bool lo  = (half == 0);

    const int wbase = b * 128 + half * 64 + tap;
    float wAr = w0r_g[wbase],      wAi = w0i_g[wbase];
    float wBr = w0r_g[wbase + 32], wBi = w0i_g[wbase + 32];

    float fr = f0r_g[b * 2 + half];
    float fi = f0i_g[b * 2 + half];
    const float invf0 = frsq(fmaf(fr, fr, fi * fi));
    float psr = fr * invf0, psm = -fi * invf0;

    const float2* __restrict__ ur2 = (const float2*)u_r + (size_t)b * kL * 32;
    const float2* __restrict__ ui2 = (const float2*)u_i + (size_t)b * kL * 32;
    const float2* __restrict__ xr2 = (const float2*)x_r + (size_t)b * kL;
    const float2* __restrict__ xi2 = (const float2*)x_i + (size_t)b * kL;
    float2* __restrict__ ob2 = (float2*)out + (size_t)b * kL * 2;

    float2 Au[kPF], Aq[kPF], AxR[kPF], AxI[kPF];
    float2 Bu[kPF], Bq[kPF], BxR[kPF], BxI[kPF];
    float suA[kPF], suB[kPF];
    float kR[kPF], kI[kPF];
    float sdpr = 0.0f, sdpi = 0.0f;

    auto loadChunk = [&](float2 (&u)[kPF], float2 (&q)[kPF],
                         float2 (&xR)[kPF], float2 (&xI)[kPF], int chunk) {
#pragma unroll
        for (int s = 0; s < kPF; ++s) {
            int t = chunk * kPF + s;
            t = t < kL ? t : kL - 1;
            u[s]  = ur2[(size_t)t * 32 + tap];
            q[s]  = ui2[(size_t)t * 32 + tap];
            xR[s] = xr2[t];
            xI[s] = xi2[t];
        }
        __builtin_amdgcn_sched_barrier(0);
    };

    auto calcSu = [&](float2 (&u)[kPF], float2 (&q)[kPF], float (&su)[kPF]) {
        float e[kPF];
#pragma unroll
        for (int s = 0; s < kPF; ++s) {
            float t0 = u[s].x * u[s].x;
            t0 = fmaf(u[s].y, u[s].y, t0);
            t0 = fmaf(q[s].x, q[s].x, t0);
            t0 = fmaf(q[s].y, q[s].y, t0);
            e[s] = t0;
        }
#pragma unroll
        for (int s = 0; s < kPF; ++s) { DPP_ADD_F32(e[s], 0x111); }
#pragma unroll
        for (int s = 0; s < kPF; ++s) { DPP_ADD_F32(e[s], 0x112); }
#pragma unroll
        for (int s = 0; s < kPF; ++s) { DPP_ADD_F32(e[s], 0x114); }
#pragma unroll
        for (int s = 0; s < kPF; ++s) { DPP_ADD_F32(e[s], 0x118); }
#pragma unroll
        for (int s = 0; s < kPF; ++s) { DPP_ADD_F32(e[s], 0x142); }
#pragma unroll
        for (int s = 0; s < kPF; ++s) su[s] = kLrW * frcp(rl(e[s], 31) + kEps);
    };

    auto body = [&](int s, float2 (&u)[kPF], float2 (&q)[kPF],
                    float2 (&xR)[kPF], float2 (&xI)[kPF], float (&su)[kPF],
                    bool first) {
        const float2 uc = u[s], qc = q[s];
        if (first) {
            const float dr0 = lo ? xR[0].x : xR[0].y;
            const float di0 = lo ? xI[0].x : xI[0].y;
            sdpr = su[0] * fmaf(dr0, psr, -di0 * psm);
            sdpi = su[0] * fmaf(dr0, psm,  di0 * psr);
        }
        float pr = wAr * uc.x;
        pr = fmaf(-wAi, qc.x, pr); pr = fmaf(wBr, uc.y, pr); pr = fmaf(-wBi, qc.y, pr);
        float pi = wAr * qc.x;
        pi = fmaf(wAi, uc.x, pi); pi = fmaf(wBr, qc.y, pi); pi = fmaf(wBi, uc.y, pi);
        DPP_ADD_F32(pr, 0x111); DPP_ADD_F32(pi, 0x111);
        DPP_ADD_F32(pr, 0x112); DPP_ADD_F32(pi, 0x112);
        DPP_ADD_F32(pr, 0x114); DPP_ADD_F32(pi, 0x114);
        DPP_ADD_F32(pr, 0x118); DPP_ADD_F32(pi, 0x118);
        DPP_ADD_F32(pr, 0x142); DPP_ADD_F32(pi, 0x142);
        const float v0r = rl(pr, 31), v1r = rl(pr, 63);
        const float v0i = rl(pi, 31), v1i = rl(pi, 63);
        const float vr = lo ? v0r : v1r;
        const float vi = lo ? v0i : v1i;

        const float sun = su[s];
        const float tr = fmaf(-sun, vr, sdpr);
        const float ti = fmaf(-sun, vi, sdpi);
        wAr = fmaf(tr, uc.x, fmaf(ti, qc.x, wAr));
        wAi = fmaf(ti, uc.x, fmaf(-tr, qc.x, wAi));
        wBr = fmaf(tr, uc.y, fmaf(ti, qc.y, wBr));
        wBi = fmaf(ti, uc.y, fmaf(-tr, qc.y, wBi));

        const float dr = lo ? xR[s].x : xR[s].y;
        const float di = lo ? xI[s].x : xI[s].y;
        const float kr = fmaf(vr, fr, -vi * fi);
        const float ki = fmaf(vr, fi,  vi * fr);
        kR[s] = kr; kI[s] = ki;
        const float efr = dr - kr, efi = di - ki;
        float ven = v0r * v0r;
        ven = fmaf(v0i, v0i, ven);
        ven = fmaf(v1r, v1r, ven);
        ven = fmaf(v1i, v1i, ven);
        const float nv = frcp(ven + kEps);
        float hr = efr * vr; hr = fmaf(efi, vi, hr);
        float hi = efi * vr; hi = fmaf(-efr, vi, hi);
        hr *= nv; hi *= nv;
        float mg = hr * hr; mg = fmaf(hi, hi, mg);
        const float sc = fminf(1.0f, kGradMax * frsq(mg));
        const float scl = kLrF * sc;
        fr = fmaf(scl, hr, fr);
        fi = fmaf(scl, hi, fi);
        const float invf = frsq(fmaf(fr, fr, fi * fi));
        psr = fr * invf; psm = -fi * invf;
        if (s + 1 < kPF) {
            const float dnr = lo ? xR[s + 1].x : xR[s + 1].y;
            const float dni = lo ? xI[s + 1].x : xI[s + 1].y;
            sdpr = su[s + 1] * fmaf(dnr, psr, -dni * psm);
            sdpi = su[s + 1] * fmaf(dnr, psm,  dni * psr);
        }
    };

    auto processChunk = [&](int tbase, float2 (&u)[kPF], float2 (&q)[kPF],
                            float2 (&xR)[kPF], float2 (&xI)[kPF], float (&su)[kPF]) {
#pragma unroll
        for (int s = 0; s < kPF; ++s)
            body(s, u, q, xR, xI, su, s == 0);
        if (tap == 0) {
#pragma unroll
            for (int s = 0; s < kPF; ++s)
                ob2[(size_t)(tbase + s) * 2 + half] = make_float2(kR[s], kI[s]);
        }
    };

    loadChunk(Au, Aq, AxR, AxI, 0);
    loadChunk(Bu, Bq, BxR, BxI, 1);
    calcSu(Au, Aq, suA);

    for (int c = 0; c < kNC; c += 2) {
        processChunk(c * kPF, Au, Aq, AxR, AxI, suA);
        loadChunk(Au, Aq, AxR, AxI, (c + 2 < kNC) ? c + 2 : kNC - 1);
        calcSu(Bu, Bq, suB);
        processChunk((c + 1) * kPF, Bu, Bq, BxR, BxI, suB);
        loadChunk(Bu, Bq, BxR, BxI, (c + 3 < kNC) ? c + 3 : kNC - 1);
        calcSu(Au, Aq, suA);
    }
}

} // namespace

extern "C" void kernel_launch(void* const* d_in, const int* in_sizes, int n_in,
                              void* d_out, int out_size, void* d_ws, size_t ws_size,
                              hipStream_t stream) {
    const float* u_r  = (const float*)d_in[0];
    const float* u_i  = (const float*)d_in[1];
    const float* x_r  = (const float*)d_in[2];
    const float* x_i  = (const float*)d_in[3];
    const float* w0_r = (const float*)d_in[4];
    const float* w0_i = (const float*)d_in[5];
    const float* f0_r = (const float*)d_in[6];
    const float* f0_i = (const float*)d_in[7];
    float* out = (float*)d_out;

    const size_t need = (size_t)kB * kL * 20;   // 1 MB su + 4 MB xd
    if (ws_size >= need) {
        float* su_ws = (float*)d_ws;
        float4* xd_ws = (float4*)((char*)d_ws + (size_t)kB * kL * 4);
        dim3 pgrid(kB * kL / 4);
        pre_kernel<<<pgrid, 256, 0, stream>>>(u_r, u_i, x_r, x_i, su_ws, xd_ws);
        adf_kernel<<<dim3(kB), dim3(64), 0, stream>>>(
            u_r, u_i, w0_r, w0_i, f0_r, f0_i, su_ws, xd_ws, out);
    } else {
        adf_fb<<<dim3(kB), dim3(64), 0, stream>>>(
            u_r, u_i, x_r, x_i, w0_r, w0_i, f0_r, f0_i, out);
    }
}